// Round 10
// baseline (177.753 us; speedup 1.0000x reference)
//
#include <hip/hip_runtime.h>
#include <cstddef>
#include <cstdint>

// ============ INSTRUMENTATION ROUND ============
// logic_main launched with 2x grid; block pairs do IDENTICAL work (same rows,
// same output values -> deterministic, duplicate writes benign). Purpose:
// push logic_main's duration above the harness fill kernels (~157us) so it
// lands in rocprof's top-5 and we finally see ITS counters, not the fills'.

constexpr int BATCH   = 4096;
constexpr int IN_DIM  = 8192;
constexpr int OUT_DIM = 16384;
constexpr int THREADS = 512;                        // 8 waves per block
constexpr int RPB     = 4;                          // batch rows per block
constexpr int NBLK    = BATCH / RPB;                // 1024 unique blocks
constexpr int GRIDX   = NBLK * 2;                   // 2x: instrumentation only
constexpr int OPT     = 4;                          // neurons per thread per chunk
constexpr int CHUNKS  = OUT_DIM / (THREADS * OPT);  // 8
constexpr int SSTEPS  = (IN_DIM / 4) / THREADS;     // 4 staging steps (f32x4 per row)

typedef float    f32x4 __attribute__((ext_vector_type(4)));
typedef uint32_t u32x2 __attribute__((ext_vector_type(2)));

__device__ __forceinline__ uint32_t f2bf(float f) {   // RNE bf16 (x in [0,1))
  uint32_t u = __float_as_uint(f);
  u += 0x7fffu + ((u >> 16) & 1u);
  return u >> 16;
}
__device__ __forceinline__ uint32_t pack_bf(float a, float b) {
  return f2bf(a) | (f2bf(b) << 16);
}
__device__ __forceinline__ float bf_lo(uint32_t u) { return __uint_as_float(u << 16); }
__device__ __forceinline__ float bf_hi(uint32_t u) { return __uint_as_float(u & 0xffff0000u); }

// softmax over 16 gate logits collapsed to (c0, ca, cb, cab); also packs idx pair
__global__ __launch_bounds__(64)
void coef_kernel(const float* __restrict__ weights,
                 const int* __restrict__ idx_a,
                 const int* __restrict__ idx_b,
                 float4* __restrict__ coef,
                 uint32_t* __restrict__ pidx) {
  const int o = blockIdx.x * 64 + threadIdx.x;
  if (o >= OUT_DIM) return;

  const float4* wp = reinterpret_cast<const float4*>(weights + (size_t)o * 16);
  float4 t0 = wp[0], t1 = wp[1], t2 = wp[2], t3 = wp[3];
  float w[16] = { t0.x, t0.y, t0.z, t0.w, t1.x, t1.y, t1.z, t1.w,
                  t2.x, t2.y, t2.z, t2.w, t3.x, t3.y, t3.z, t3.w };
  float m = w[0];
#pragma unroll
  for (int i = 1; i < 16; ++i) m = fmaxf(m, w[i]);
  float p[16]; float s = 0.f;
#pragma unroll
  for (int i = 0; i < 16; ++i) { p[i] = __expf(w[i] - m); s += p[i]; }
  const float inv = 1.0f / s;
  const float GC[16]  = {0,0,0,0, 0,0,0,0, 1,1,1,1, 1,1,1,1};
  const float GA[16]  = {0,0,1,1, 0,0,1,1, -1,-1,0,0, -1,-1,0,0};
  const float GB[16]  = {0,0,0,0, 1,1,1,1, -1,-1,-1,-1, 0,0,0,0};
  const float GAB[16] = {0,1,-1,0, -1,0,-2,-1, 1,2,0,1, 0,1,-1,0};
  float c0 = 0.f, ca = 0.f, cb = 0.f, cab = 0.f;
#pragma unroll
  for (int i = 0; i < 16; ++i) {
    c0 += p[i] * GC[i]; ca += p[i] * GA[i];
    cb += p[i] * GB[i]; cab += p[i] * GAB[i];
  }
  coef[o] = make_float4(c0 * inv, ca * inv, cb * inv, cab * inv);
  pidx[o] = (uint32_t)idx_a[o] | ((uint32_t)idx_b[o] << 16);
}

// 2-row affine eval from one packed bf16-pair of a and b; returns {lo-row, hi-row}
__device__ __forceinline__ float2 eval2(float4 c, uint32_t ga, uint32_t gb) {
  const float a0 = bf_lo(ga), b0 = bf_lo(gb);
  const float a1 = bf_hi(ga), b1 = bf_hi(gb);
  float2 r;
  r.x = fmaf(fmaf(c.w, a0, c.z), b0, fmaf(c.y, a0, c.x));
  r.y = fmaf(fmaf(c.w, a1, c.z), b1, fmaf(c.y, a1, c.x));
  return r;
}

__global__ __launch_bounds__(THREADS)
void logic_main(const float* __restrict__ x,
                const float4* __restrict__ coef,
                const uint32_t* __restrict__ pidx,
                float* __restrict__ out) {
  // 4-row packed: xq[i] = { bf(r0[i]) | bf(r1[i])<<16 , bf(r2[i]) | bf(r3[i])<<16 }
  __shared__ u32x2 xq[IN_DIM];                      // 64 KB -> 2 blocks/CU

  const int t  = threadIdx.x;
  // INSTRUMENTATION: block pairs (i, i+NBLK) do identical work.
  const int b0 = (blockIdx.x & (NBLK - 1)) * RPB;

  const f32x4* __restrict__ r0 =
      reinterpret_cast<const f32x4*>(x + (size_t)(b0 + 0) * IN_DIM);
  const f32x4* __restrict__ r1 =
      reinterpret_cast<const f32x4*>(x + (size_t)(b0 + 1) * IN_DIM);
  const f32x4* __restrict__ r2 =
      reinterpret_cast<const f32x4*>(x + (size_t)(b0 + 2) * IN_DIM);
  const f32x4* __restrict__ r3 =
      reinterpret_cast<const f32x4*>(x + (size_t)(b0 + 3) * IN_DIM);

  // prefetch chunk-0 operands (hide L2 latency under staging)
  int o0 = t * OPT;
  int4   pi = *reinterpret_cast<const int4*>(pidx + o0);
  float4 c0 = coef[o0 + 0], c1 = coef[o0 + 1],
         c2 = coef[o0 + 2], c3 = coef[o0 + 3];

  // ---- stage 4 rows, 4-row-packed ----
#pragma unroll
  for (int s = 0; s < SSTEPS; ++s) {
    const int q = s * THREADS + t;                  // f32x4 index (elems 4q..4q+3)
    f32x4 a = r0[q], b = r1[q], c = r2[q], d = r3[q];
    u32x2 p0, p1, p2, p3;
    p0.x = pack_bf(a.x, b.x); p0.y = pack_bf(c.x, d.x);
    p1.x = pack_bf(a.y, b.y); p1.y = pack_bf(c.y, d.y);
    p2.x = pack_bf(a.z, b.z); p2.y = pack_bf(c.z, d.z);
    p3.x = pack_bf(a.w, b.w); p3.y = pack_bf(c.w, d.w);
    xq[4 * q + 0] = p0;
    xq[4 * q + 1] = p1;
    xq[4 * q + 2] = p2;
    xq[4 * q + 3] = p3;
  }
  __syncthreads();

#pragma unroll 2
  for (int ch = 0; ch < CHUNKS; ++ch) {
    const int o = ch * (THREADS * OPT) + t * OPT;

    const uint32_t i0a = (uint32_t)pi.x & 0xffffu, i0b = (uint32_t)pi.x >> 16;
    const uint32_t i1a = (uint32_t)pi.y & 0xffffu, i1b = (uint32_t)pi.y >> 16;
    const uint32_t i2a = (uint32_t)pi.z & 0xffffu, i2b = (uint32_t)pi.z >> 16;
    const uint32_t i3a = (uint32_t)pi.w & 0xffffu, i3b = (uint32_t)pi.w >> 16;

    // 8 ds_read_b64 gathers: each serves 4 rows
    const u32x2 g0a = xq[i0a], g0b = xq[i0b];
    const u32x2 g1a = xq[i1a], g1b = xq[i1b];
    const u32x2 g2a = xq[i2a], g2b = xq[i2b];
    const u32x2 g3a = xq[i3a], g3b = xq[i3b];

    const float2 e0lo = eval2(c0, g0a.x, g0b.x), e0hi = eval2(c0, g0a.y, g0b.y);
    const float2 e1lo = eval2(c1, g1a.x, g1b.x), e1hi = eval2(c1, g1a.y, g1b.y);
    const float2 e2lo = eval2(c2, g2a.x, g2b.x), e2hi = eval2(c2, g2a.y, g2b.y);
    const float2 e3lo = eval2(c3, g3a.x, g3b.x), e3hi = eval2(c3, g3a.y, g3b.y);

    f32x4 res0, res1, res2, res3;
    res0.x = e0lo.x; res0.y = e1lo.x; res0.z = e2lo.x; res0.w = e3lo.x;
    res1.x = e0lo.y; res1.y = e1lo.y; res1.z = e2lo.y; res1.w = e3lo.y;
    res2.x = e0hi.x; res2.y = e1hi.x; res2.z = e2hi.x; res2.w = e3hi.x;
    res3.x = e0hi.y; res3.y = e1hi.y; res3.z = e2hi.y; res3.w = e3hi.y;

    // prefetch next chunk's operands before the stores
    if (ch + 1 < CHUNKS) {
      const int on = o + THREADS * OPT;
      pi = *reinterpret_cast<const int4*>(pidx + on);
      c0 = coef[on + 0]; c1 = coef[on + 1];
      c2 = coef[on + 2]; c3 = coef[on + 3];
    }

    *reinterpret_cast<f32x4*>(out + (size_t)(b0 + 0) * OUT_DIM + o) = res0;
    *reinterpret_cast<f32x4*>(out + (size_t)(b0 + 1) * OUT_DIM + o) = res1;
    *reinterpret_cast<f32x4*>(out + (size_t)(b0 + 2) * OUT_DIM + o) = res2;
    *reinterpret_cast<f32x4*>(out + (size_t)(b0 + 3) * OUT_DIM + o) = res3;
  }
}

extern "C" void kernel_launch(void* const* d_in, const int* in_sizes, int n_in,
                              void* d_out, int out_size, void* d_ws, size_t ws_size,
                              hipStream_t stream) {
  const float* x       = (const float*)d_in[0];
  const float* weights = (const float*)d_in[1];
  const int*   idx_a   = (const int*)d_in[2];
  const int*   idx_b   = (const int*)d_in[3];
  float*       out     = (float*)d_out;

  float4*   coef = (float4*)d_ws;                                   // 256 KB
  uint32_t* pidx = (uint32_t*)((char*)d_ws + (size_t)OUT_DIM * 16); // +64 KB

  coef_kernel<<<OUT_DIM / 64, 64, 0, stream>>>(weights, idx_a, idx_b, coef, pidx);
  logic_main<<<GRIDX, THREADS, 0, stream>>>(x, coef, pidx, out);
}

// Round 11
// 96.712 us; speedup vs baseline: 1.8380x; 1.8380x over previous
//
#include <hip/hip_runtime.h>
#include <cstddef>
#include <cstdint>

constexpr int BATCH   = 4096;
constexpr int IN_DIM  = 8192;
constexpr int OUT_DIM = 16384;
constexpr int THREADS = 1024;                       // 16 waves per block
constexpr int RPB     = 4;                          // batch rows per block
constexpr int NBLK    = BATCH / RPB;                // 1024 blocks
constexpr int OPT     = 4;                          // neurons per thread per chunk
constexpr int CHUNKS  = OUT_DIM / (THREADS * OPT);  // 4
constexpr int SSTEPS  = (IN_DIM / 4) / THREADS;     // 2 staging steps (f32x4 per row)

typedef float    f32x4 __attribute__((ext_vector_type(4)));
typedef uint32_t u32x2 __attribute__((ext_vector_type(2)));

__device__ __forceinline__ uint32_t f2bf(float f) {   // RNE bf16 (x in [0,1))
  uint32_t u = __float_as_uint(f);
  u += 0x7fffu + ((u >> 16) & 1u);
  return u >> 16;
}
__device__ __forceinline__ uint32_t pack_bf(float a, float b) {
  return f2bf(a) | (f2bf(b) << 16);
}
__device__ __forceinline__ float bf_lo(uint32_t u) { return __uint_as_float(u << 16); }
__device__ __forceinline__ float bf_hi(uint32_t u) { return __uint_as_float(u & 0xffff0000u); }

// softmax over 16 gate logits collapsed to (c0, ca, cb, cab); also packs idx pair
__global__ __launch_bounds__(64)
void coef_kernel(const float* __restrict__ weights,
                 const int* __restrict__ idx_a,
                 const int* __restrict__ idx_b,
                 float4* __restrict__ coef,
                 uint32_t* __restrict__ pidx) {
  const int o = blockIdx.x * 64 + threadIdx.x;
  if (o >= OUT_DIM) return;

  const float4* wp = reinterpret_cast<const float4*>(weights + (size_t)o * 16);
  float4 t0 = wp[0], t1 = wp[1], t2 = wp[2], t3 = wp[3];
  float w[16] = { t0.x, t0.y, t0.z, t0.w, t1.x, t1.y, t1.z, t1.w,
                  t2.x, t2.y, t2.z, t2.w, t3.x, t3.y, t3.z, t3.w };
  float m = w[0];
#pragma unroll
  for (int i = 1; i < 16; ++i) m = fmaxf(m, w[i]);
  float p[16]; float s = 0.f;
#pragma unroll
  for (int i = 0; i < 16; ++i) { p[i] = __expf(w[i] - m); s += p[i]; }
  const float inv = 1.0f / s;
  const float GC[16]  = {0,0,0,0, 0,0,0,0, 1,1,1,1, 1,1,1,1};
  const float GA[16]  = {0,0,1,1, 0,0,1,1, -1,-1,0,0, -1,-1,0,0};
  const float GB[16]  = {0,0,0,0, 1,1,1,1, -1,-1,-1,-1, 0,0,0,0};
  const float GAB[16] = {0,1,-1,0, -1,0,-2,-1, 1,2,0,1, 0,1,-1,0};
  float c0 = 0.f, ca = 0.f, cb = 0.f, cab = 0.f;
#pragma unroll
  for (int i = 0; i < 16; ++i) {
    c0 += p[i] * GC[i]; ca += p[i] * GA[i];
    cb += p[i] * GB[i]; cab += p[i] * GAB[i];
  }
  coef[o] = make_float4(c0 * inv, ca * inv, cb * inv, cab * inv);
  pidx[o] = (uint32_t)idx_a[o] | ((uint32_t)idx_b[o] << 16);
}

// 2-row affine eval from one packed bf16-pair of a and b; returns {lo-row, hi-row}
__device__ __forceinline__ float2 eval2(float4 c, uint32_t ga, uint32_t gb) {
  const float a0 = bf_lo(ga), b0 = bf_lo(gb);
  const float a1 = bf_hi(ga), b1 = bf_hi(gb);
  float2 r;
  r.x = fmaf(fmaf(c.w, a0, c.z), b0, fmaf(c.y, a0, c.x));
  r.y = fmaf(fmaf(c.w, a1, c.z), b1, fmaf(c.y, a1, c.x));
  return r;
}

__global__ __launch_bounds__(THREADS, 8)            // cap VGPR<=64: 2 blocks/CU, 32 waves
void logic_main(const float* __restrict__ x,
                const float4* __restrict__ coef,
                const uint32_t* __restrict__ pidx,
                float* __restrict__ out) {
  // 4-row packed: xq[i] = { bf(r0[i]) | bf(r1[i])<<16 , bf(r2[i]) | bf(r3[i])<<16 }
  __shared__ u32x2 xq[IN_DIM];                      // 64 KB -> 2 blocks/CU

  const int t  = threadIdx.x;
  const int b0 = blockIdx.x * RPB;

  const f32x4* __restrict__ r0 =
      reinterpret_cast<const f32x4*>(x + (size_t)(b0 + 0) * IN_DIM);
  const f32x4* __restrict__ r1 =
      reinterpret_cast<const f32x4*>(x + (size_t)(b0 + 1) * IN_DIM);
  const f32x4* __restrict__ r2 =
      reinterpret_cast<const f32x4*>(x + (size_t)(b0 + 2) * IN_DIM);
  const f32x4* __restrict__ r3 =
      reinterpret_cast<const f32x4*>(x + (size_t)(b0 + 3) * IN_DIM);

  // prefetch chunk-0 operands (hide L2 latency under staging)
  int o0 = t * OPT;
  int4   pi = *reinterpret_cast<const int4*>(pidx + o0);
  float4 c0 = coef[o0 + 0], c1 = coef[o0 + 1],
         c2 = coef[o0 + 2], c3 = coef[o0 + 3];

  // ---- stage 4 rows, 4-row-packed ----
#pragma unroll
  for (int s = 0; s < SSTEPS; ++s) {
    const int q = s * THREADS + t;                  // f32x4 index (elems 4q..4q+3)
    f32x4 a = r0[q], b = r1[q], c = r2[q], d = r3[q];
    u32x2 p0, p1, p2, p3;
    p0.x = pack_bf(a.x, b.x); p0.y = pack_bf(c.x, d.x);
    p1.x = pack_bf(a.y, b.y); p1.y = pack_bf(c.y, d.y);
    p2.x = pack_bf(a.z, b.z); p2.y = pack_bf(c.z, d.z);
    p3.x = pack_bf(a.w, b.w); p3.y = pack_bf(c.w, d.w);
    xq[4 * q + 0] = p0;
    xq[4 * q + 1] = p1;
    xq[4 * q + 2] = p2;
    xq[4 * q + 3] = p3;
  }
  __syncthreads();

#pragma unroll
  for (int ch = 0; ch < CHUNKS; ++ch) {
    const int o = ch * (THREADS * OPT) + t * OPT;

    const uint32_t i0a = (uint32_t)pi.x & 0xffffu, i0b = (uint32_t)pi.x >> 16;
    const uint32_t i1a = (uint32_t)pi.y & 0xffffu, i1b = (uint32_t)pi.y >> 16;
    const uint32_t i2a = (uint32_t)pi.z & 0xffffu, i2b = (uint32_t)pi.z >> 16;
    const uint32_t i3a = (uint32_t)pi.w & 0xffffu, i3b = (uint32_t)pi.w >> 16;

    // 8 ds_read_b64 gathers: each serves 4 rows
    const u32x2 g0a = xq[i0a], g0b = xq[i0b];
    const u32x2 g1a = xq[i1a], g1b = xq[i1b];
    const u32x2 g2a = xq[i2a], g2b = xq[i2b];
    const u32x2 g3a = xq[i3a], g3b = xq[i3b];

    const float2 e0lo = eval2(c0, g0a.x, g0b.x), e0hi = eval2(c0, g0a.y, g0b.y);
    const float2 e1lo = eval2(c1, g1a.x, g1b.x), e1hi = eval2(c1, g1a.y, g1b.y);
    const float2 e2lo = eval2(c2, g2a.x, g2b.x), e2hi = eval2(c2, g2a.y, g2b.y);
    const float2 e3lo = eval2(c3, g3a.x, g3b.x), e3hi = eval2(c3, g3a.y, g3b.y);

    f32x4 res0, res1, res2, res3;
    res0.x = e0lo.x; res0.y = e1lo.x; res0.z = e2lo.x; res0.w = e3lo.x;
    res1.x = e0lo.y; res1.y = e1lo.y; res1.z = e2lo.y; res1.w = e3lo.y;
    res2.x = e0hi.x; res2.y = e1hi.x; res2.z = e2hi.x; res2.w = e3hi.x;
    res3.x = e0hi.y; res3.y = e1hi.y; res3.z = e2hi.y; res3.w = e3hi.y;

    // prefetch next chunk's operands before the stores
    if (ch + 1 < CHUNKS) {
      const int on = o + THREADS * OPT;
      pi = *reinterpret_cast<const int4*>(pidx + on);
      c0 = coef[on + 0]; c1 = coef[on + 1];
      c2 = coef[on + 2]; c3 = coef[on + 3];
    }

    *reinterpret_cast<f32x4*>(out + (size_t)(b0 + 0) * OUT_DIM + o) = res0;
    *reinterpret_cast<f32x4*>(out + (size_t)(b0 + 1) * OUT_DIM + o) = res1;
    *reinterpret_cast<f32x4*>(out + (size_t)(b0 + 2) * OUT_DIM + o) = res2;
    *reinterpret_cast<f32x4*>(out + (size_t)(b0 + 3) * OUT_DIM + o) = res3;
  }
}

extern "C" void kernel_launch(void* const* d_in, const int* in_sizes, int n_in,
                              void* d_out, int out_size, void* d_ws, size_t ws_size,
                              hipStream_t stream) {
  const float* x       = (const float*)d_in[0];
  const float* weights = (const float*)d_in[1];
  const int*   idx_a   = (const int*)d_in[2];
  const int*   idx_b   = (const int*)d_in[3];
  float*       out     = (float*)d_out;

  float4*   coef = (float4*)d_ws;                                   // 256 KB
  uint32_t* pidx = (uint32_t*)((char*)d_ws + (size_t)OUT_DIM * 16); // +64 KB

  coef_kernel<<<OUT_DIM / 64, 64, 0, stream>>>(weights, idx_a, idx_b, coef, pidx);
  logic_main<<<NBLK, THREADS, 0, stream>>>(x, coef, pidx, out);
}